// Round 1
// baseline (607.062 us; speedup 1.0000x reference)
//
#include <hip/hip_runtime.h>

// Problem constants
#define VOCAB 50000
#define EMB   300
#define HID   16
#define OUTD  5
#define BSZ   128
#define SEQ   512
#define NTOK  (BSZ*SEQ)

// ws layout (in floats):
//   [0 .. 19200)        wt   : w_ih transposed -> [e][j] (300 x 64)
//   [19200 .. 19264)    bias : b_ih + b_hh (64)
//   [19264 .. +4194304) pre  : pre-gates [tok][u][4] (i,f,g,o per unit)
//   [.. +2048)          pad  : prefetch overrun guard
#define WT_OFF   0
#define BIAS_OFF 19200
#define PRE_OFF  19264
#define PRE_PAD  2048

// ---------------- kernel 0: transpose w_ih, fold bias ----------------
__global__ __launch_bounds__(256) void k0_prep(
    const float* __restrict__ w_ih, const float* __restrict__ b_ih,
    const float* __restrict__ b_hh, float* __restrict__ wt,
    float* __restrict__ bias)
{
  int i = blockIdx.x * 256 + threadIdx.x;
  if (i < 64*EMB) {
    int j = i / EMB;          // gate row
    int e = i - j * EMB;      // emb col
    wt[e * 64 + j] = w_ih[i]; // coalesced read, scattered write (write-buffered)
  }
  if (i < 64) bias[i] = b_ih[i] + b_hh[i];
}

// ---------------- kernel 1: gather + input GEMM ----------------
// One wave = 64 tokens (lane = token). Gate loop j=0..63 kept in registers
// as 64 accumulators; w row values are wave-uniform loads (scalarizable).
__global__ __launch_bounds__(256) void k1_pregates(
    const int* __restrict__ x, const float* __restrict__ emb,
    const float* __restrict__ wt, const float* __restrict__ bias,
    float* __restrict__ pre)
{
  const int wave = threadIdx.x >> 6;
  const int lane = threadIdx.x & 63;
  const int tok  = (blockIdx.x * 4 + wave) * 64 + lane;   // < 65536

  const int row = x[tok];
  const float4* __restrict__ er4 = (const float4*)(emb + (size_t)row * EMB); // 1200B rows -> 16B aligned
  const float4* __restrict__ wt4 = (const float4*)wt;     // [300][16] float4

  float acc[64];
  #pragma unroll
  for (int j = 0; j < 64; ++j) acc[j] = 0.f;

  for (int e4 = 0; e4 < EMB/4; ++e4) {   // 75 iters
    float4 ev = er4[e4];                 // per-lane gather (16B)
    #pragma unroll
    for (int ee = 0; ee < 4; ++ee) {
      float evs = (ee==0) ? ev.x : (ee==1) ? ev.y : (ee==2) ? ev.z : ev.w;
      const float4* wr = wt4 + (e4*4 + ee) * 16;   // wave-uniform address
      #pragma unroll
      for (int q = 0; q < 16; ++q) {
        float4 wv = wr[q];
        acc[4*q+0] = fmaf(evs, wv.x, acc[4*q+0]);
        acc[4*q+1] = fmaf(evs, wv.y, acc[4*q+1]);
        acc[4*q+2] = fmaf(evs, wv.z, acc[4*q+2]);
        acc[4*q+3] = fmaf(evs, wv.w, acc[4*q+3]);
      }
    }
  }

  // add bias; store permuted as [tok][u][4] = (i,f,g,o) so k2 reads one float4
  float4* __restrict__ pre4 = (float4*)pre;
  #pragma unroll
  for (int u = 0; u < 16; ++u) {
    float4 o;
    o.x = acc[u]      + bias[u];        // i
    o.y = acc[16+u]   + bias[16+u];     // f
    o.z = acc[32+u]   + bias[32+u];     // g
    o.w = acc[48+u]   + bias[48+u];     // o
    pre4[(size_t)tok * 16 + u] = o;
  }
}

// ---------------- kernel 2: recurrence + pooling + linear ----------------
__device__ __forceinline__ float sigf(float x) {
  return 1.f / (1.f + __expf(-x));
}
__device__ __forceinline__ float tanh_fast(float x) {
  float e = __expf(-2.f * fabsf(x));       // e in (0,1], overflow-safe
  float t = (1.f - e) / (1.f + e);
  return copysignf(t, x);
}

__global__ __launch_bounds__(256) void k2_lstm(
    const int* __restrict__ lengths,
    const float* __restrict__ w_hh,
    const float* __restrict__ w_lin,
    const float* __restrict__ b_lin,
    const float* __restrict__ pre,
    float* __restrict__ out)
{
  const int tid = threadIdx.x;
  const int u  = tid & 15;        // hidden unit
  const int bl = tid >> 4;        // local batch (0..15)
  const int b  = blockIdx.x * 16 + bl;

  // preload w_hh rows u, 16+u, 32+u, 48+u into registers (64 floats)
  const float4* __restrict__ wh4 = (const float4*)w_hh;
  float wi[16], wf[16], wg[16], wo[16];
  #pragma unroll
  for (int q = 0; q < 4; ++q) {
    float4 t;
    t = wh4[(0*HID+u)*4+q]; wi[4*q]=t.x; wi[4*q+1]=t.y; wi[4*q+2]=t.z; wi[4*q+3]=t.w;
    t = wh4[(1*HID+u)*4+q]; wf[4*q]=t.x; wf[4*q+1]=t.y; wf[4*q+2]=t.z; wf[4*q+3]=t.w;
    t = wh4[(2*HID+u)*4+q]; wg[4*q]=t.x; wg[4*q+1]=t.y; wg[4*q+2]=t.z; wg[4*q+3]=t.w;
    t = wh4[(3*HID+u)*4+q]; wo[4*q]=t.x; wo[4*q+1]=t.y; wo[4*q+2]=t.z; wo[4*q+3]=t.w;
  }

  int L = lengths[b];
  L = (L < 1) ? 1 : (L > SEQ ? SEQ : L);

  // wave-level max length (4 batches per wave) for early exit
  int Lw = L;
  Lw = max(Lw, __shfl_xor(Lw, 16, 64));
  Lw = max(Lw, __shfl_xor(Lw, 32, 64));

  const float4* __restrict__ pp = (const float4*)pre + (size_t)b * SEQ * 16 + u;

  float h = 0.f, c = 0.f;
  float s_sum = 0.f, s_max = -3.4e38f, s_last = 0.f;

  // software pipeline: 8-deep prefetch (covers HBM/L2 latency under ~8 steps of compute)
  float4 buf[8];
  #pragma unroll
  for (int p = 0; p < 8; ++p) buf[p] = pp[(size_t)p * 16];

  for (int g = 0; g < SEQ/8; ++g) {
    if (g * 8 >= Lw) break;    // wave-uniform early exit
    #pragma unroll
    for (int p = 0; p < 8; ++p) {
      float4 cur = buf[p];
      buf[p] = pp[((size_t)(g+1)*8 + p) * 16];   // prefetch (pad covers g=63 overrun)
      const int s = g*8 + p;

      float gi = cur.x, gf = cur.y, gg = cur.z, go = cur.w;
      #pragma unroll
      for (int k = 0; k < 16; ++k) {
        float hk = __shfl(h, k, 16);   // broadcast h[k] within 16-lane batch group
        gi = fmaf(wi[k], hk, gi);
        gf = fmaf(wf[k], hk, gf);
        gg = fmaf(wg[k], hk, gg);
        go = fmaf(wo[k], hk, go);
      }
      gi = sigf(gi);
      gf = sigf(gf);
      gg = tanh_fast(gg);
      go = sigf(go);
      c = fmaf(gf, c, gi * gg);
      h = go * tanh_fast(c);

      bool act = (s < L);
      s_sum  += act ? h : 0.f;
      s_max   = act ? fmaxf(s_max, h) : s_max;
      s_last  = (s == L - 1) ? h : s_last;
    }
  }

  // stage rep = [last(16) | sum(16) | max(16)] per batch, then 48->5 linear
  __shared__ float rep[16][48];
  rep[bl][u]      = s_last;
  rep[bl][16 + u] = s_sum;
  rep[bl][32 + u] = s_max;
  __syncthreads();

  if (tid < 16 * OUTD) {
    int bo = tid / OUTD;       // local batch
    int o  = tid % OUTD;       // output idx
    float acc = b_lin[o];
    #pragma unroll
    for (int k = 0; k < 48; ++k)
      acc = fmaf(rep[bo][k], w_lin[o * 48 + k], acc);
    out[(blockIdx.x * 16 + bo) * OUTD + o] = acc;
  }
}

// ---------------- launcher ----------------
extern "C" void kernel_launch(void* const* d_in, const int* in_sizes, int n_in,
                              void* d_out, int out_size, void* d_ws, size_t ws_size,
                              hipStream_t stream)
{
  const int*   x      = (const int*)d_in[0];
  const int*   lens   = (const int*)d_in[1];
  const float* emb    = (const float*)d_in[2];
  const float* w_ih   = (const float*)d_in[3];
  const float* w_hh   = (const float*)d_in[4];
  const float* b_ih   = (const float*)d_in[5];
  const float* b_hh   = (const float*)d_in[6];
  const float* w_lin  = (const float*)d_in[7];
  const float* b_lin  = (const float*)d_in[8];
  float* out = (float*)d_out;

  float* ws   = (float*)d_ws;
  float* wt   = ws + WT_OFF;
  float* bias = ws + BIAS_OFF;
  float* pre  = ws + PRE_OFF;

  hipLaunchKernelGGL(k0_prep,     dim3(75),  dim3(256), 0, stream, w_ih, b_ih, b_hh, wt, bias);
  hipLaunchKernelGGL(k1_pregates, dim3(256), dim3(256), 0, stream, x, emb, wt, bias, pre);
  hipLaunchKernelGGL(k2_lstm,     dim3(8),   dim3(256), 0, stream, lens, w_hh, w_lin, b_lin, pre, out);
}

// Round 3
// 443.500 us; speedup vs baseline: 1.3688x; 1.3688x over previous
//
#include <hip/hip_runtime.h>

// Problem constants
#define VOCAB 50000
#define EMB   300
#define HID   16
#define OUTD  5
#define BSZ   128
#define SEQ   512
#define NTOK  (BSZ*SEQ)

// ws layout (in floats):
//   [0 .. 19200)     wt     : w_ih re-transposed -> [e][u][g]  (300 x 16 x 4)
//   [19200 .. 19264) bias_t : (b_ih+b_hh) permuted [u][g]
//   [19264 .. +16M)  pre    : pre-gates [tok][u][4] (i,f,g,o per unit)
//   [.. +2048)       pad    : k2 prefetch overrun guard
#define WT_OFF   0
#define BIAS_OFF 19200
#define PRE_OFF  19264
#define PRE_PAD  2048

// ---------------- kernel 0: permute w_ih -> [e][u][g], fold bias ----------------
__global__ __launch_bounds__(256) void k0_prep(
    const float* __restrict__ w_ih, const float* __restrict__ b_ih,
    const float* __restrict__ b_hh, float* __restrict__ wt,
    float* __restrict__ bias_t)
{
  int i = blockIdx.x * 256 + threadIdx.x;
  if (i < 64*EMB) {
    int g = i / (16*EMB);              // gate type (i,f,g,o)
    int r = i - g * (16*EMB);
    int u = r / EMB;                   // unit
    int e = r - u * EMB;               // emb col
    wt[e * 64 + u * 4 + g] = w_ih[i];  // coalesced read
  }
  if (i < 64) {
    int u = i >> 2, g = i & 3;
    bias_t[i] = b_ih[g*16+u] + b_hh[g*16+u];
  }
}

// ---------------- kernel 1: gather + input GEMM (gate-quarter split) ----------------
// 1024 blocks x 256 threads. Block handles 64 tokens; wave q computes units
// [4q,4q+4) (all 4 gate types) for those tokens. Lane = token -> coalesced
// gather; weight loads are wave-uniform (L1-resident, 19.2KB per quarter).
__global__ __launch_bounds__(256) void k1_pregates(
    const int* __restrict__ x, const float* __restrict__ emb,
    const float* __restrict__ wt, const float* __restrict__ bias_t,
    float* __restrict__ pre)
{
  const int q    = threadIdx.x >> 6;        // unit quarter 0..3
  const int lane = threadIdx.x & 63;
  const int tok  = blockIdx.x * 64 + lane;  // < 65536

  const int row = x[tok];
  const float4* __restrict__ er4 = (const float4*)(emb + (size_t)row * EMB); // 1200B rows, 16B aligned
  const float4* __restrict__ wt4 = (const float4*)wt;   // [300][16] float4 (unit-major, gate in vec)

  float4 acc0 = {0,0,0,0}, acc1 = {0,0,0,0}, acc2 = {0,0,0,0}, acc3 = {0,0,0,0};

  for (int e4 = 0; e4 < EMB/4; ++e4) {   // 75 iters
    float4 ev = er4[e4];                 // per-lane gather (16B)
    #pragma unroll
    for (int ee = 0; ee < 4; ++ee) {
      float evs = (ee==0) ? ev.x : (ee==1) ? ev.y : (ee==2) ? ev.z : ev.w;
      const float4* wr = wt4 + (size_t)(e4*4 + ee) * 16 + q * 4;  // wave-uniform
      float4 w0 = wr[0], w1 = wr[1], w2 = wr[2], w3 = wr[3];
      acc0.x = fmaf(evs, w0.x, acc0.x); acc0.y = fmaf(evs, w0.y, acc0.y);
      acc0.z = fmaf(evs, w0.z, acc0.z); acc0.w = fmaf(evs, w0.w, acc0.w);
      acc1.x = fmaf(evs, w1.x, acc1.x); acc1.y = fmaf(evs, w1.y, acc1.y);
      acc1.z = fmaf(evs, w1.z, acc1.z); acc1.w = fmaf(evs, w1.w, acc1.w);
      acc2.x = fmaf(evs, w2.x, acc2.x); acc2.y = fmaf(evs, w2.y, acc2.y);
      acc2.z = fmaf(evs, w2.z, acc2.z); acc2.w = fmaf(evs, w2.w, acc2.w);
      acc3.x = fmaf(evs, w3.x, acc3.x); acc3.y = fmaf(evs, w3.y, acc3.y);
      acc3.z = fmaf(evs, w3.z, acc3.z); acc3.w = fmaf(evs, w3.w, acc3.w);
    }
  }

  const float4* __restrict__ bias4 = (const float4*)bias_t;  // [16] float4
  float4* __restrict__ pre4 = (float4*)pre;
  float4 b0 = bias4[q*4+0], b1 = bias4[q*4+1], b2 = bias4[q*4+2], b3 = bias4[q*4+3];
  acc0.x += b0.x; acc0.y += b0.y; acc0.z += b0.z; acc0.w += b0.w;
  acc1.x += b1.x; acc1.y += b1.y; acc1.z += b1.z; acc1.w += b1.w;
  acc2.x += b2.x; acc2.y += b2.y; acc2.z += b2.z; acc2.w += b2.w;
  acc3.x += b3.x; acc3.y += b3.y; acc3.z += b3.z; acc3.w += b3.w;
  size_t base = (size_t)tok * 16 + q * 4;
  pre4[base+0] = acc0; pre4[base+1] = acc1; pre4[base+2] = acc2; pre4[base+3] = acc3;
}

// ---------------- kernel 2: recurrence + pooling + linear ----------------
__device__ __forceinline__ float sigf(float x) {
  return 1.f / (1.f + __expf(-x));
}
__device__ __forceinline__ float tanh_fast(float x) {
  float e = __expf(-2.f * fabsf(x));       // e in (0,1], overflow-safe
  float t = (1.f - e) / (1.f + e);
  return copysignf(t, x);
}

// 32 blocks x 64 threads: one wave handles 4 batches x 16 units.
// h-broadcast is a wave-synchronous LDS round trip (DS ops are in-order
// within a wave; batch's 16 units are all in this wave -> no barrier).
__global__ __launch_bounds__(64) void k2_lstm(
    const int* __restrict__ lengths,
    const float* __restrict__ w_hh,
    const float* __restrict__ w_lin,
    const float* __restrict__ b_lin,
    const float* __restrict__ pre,
    float* __restrict__ out)
{
  const int tid = threadIdx.x;
  const int u  = tid & 15;        // hidden unit
  const int bl = tid >> 4;        // local batch (0..3)
  const int b  = blockIdx.x * 4 + bl;

  // preload w_hh rows u, 16+u, 32+u, 48+u into registers (64 floats)
  const float4* __restrict__ wh4 = (const float4*)w_hh;
  float wi[16], wf[16], wg[16], wo[16];
  #pragma unroll
  for (int qq = 0; qq < 4; ++qq) {
    float4 t;
    t = wh4[(0*HID+u)*4+qq]; wi[4*qq]=t.x; wi[4*qq+1]=t.y; wi[4*qq+2]=t.z; wi[4*qq+3]=t.w;
    t = wh4[(1*HID+u)*4+qq]; wf[4*qq]=t.x; wf[4*qq+1]=t.y; wf[4*qq+2]=t.z; wf[4*qq+3]=t.w;
    t = wh4[(2*HID+u)*4+qq]; wg[4*qq]=t.x; wg[4*qq+1]=t.y; wg[4*qq+2]=t.z; wg[4*qq+3]=t.w;
    t = wh4[(3*HID+u)*4+qq]; wo[4*qq]=t.x; wo[4*qq+1]=t.y; wo[4*qq+2]=t.z; wo[4*qq+3]=t.w;
  }

  int L = lengths[b];
  L = (L < 1) ? 1 : (L > SEQ ? SEQ : L);

  // wave-level max length (4 batches in this wave) for early exit
  int Lw = L;
  Lw = max(Lw, __shfl_xor(Lw, 16, 64));
  Lw = max(Lw, __shfl_xor(Lw, 32, 64));

  const float4* __restrict__ pp = (const float4*)pre + (size_t)b * SEQ * 16 + u;

  __shared__ float hbuf[4][16];

  float h = 0.f, c = 0.f;
  float s_sum = 0.f, s_max = -3.4e38f, s_last = 0.f;

  // software pipeline: 8-deep prefetch
  float4 buf[8];
  #pragma unroll
  for (int p = 0; p < 8; ++p) buf[p] = pp[(size_t)p * 16];

  for (int g = 0; g < SEQ/8; ++g) {
    if (g * 8 >= Lw) break;    // wave-uniform early exit
    #pragma unroll
    for (int p = 0; p < 8; ++p) {
      float4 cur = buf[p];
      buf[p] = pp[((size_t)(g+1)*8 + p) * 16];   // prefetch (pad covers overrun)
      const int s = g*8 + p;

      // wave-synchronous h broadcast: 1 ds_write + 4 ds_read_b128
      hbuf[bl][u] = h;
      __builtin_amdgcn_wave_barrier();
      float4 h0 = ((const float4*)hbuf[bl])[0];
      float4 h1 = ((const float4*)hbuf[bl])[1];
      float4 h2 = ((const float4*)hbuf[bl])[2];
      float4 h3 = ((const float4*)hbuf[bl])[3];
      __builtin_amdgcn_wave_barrier();
      float hh[16] = {h0.x,h0.y,h0.z,h0.w, h1.x,h1.y,h1.z,h1.w,
                      h2.x,h2.y,h2.z,h2.w, h3.x,h3.y,h3.z,h3.w};

      float gi = cur.x, gf = cur.y, gg = cur.z, go = cur.w;
      #pragma unroll
      for (int k = 0; k < 16; ++k) {
        gi = fmaf(wi[k], hh[k], gi);
        gf = fmaf(wf[k], hh[k], gf);
        gg = fmaf(wg[k], hh[k], gg);
        go = fmaf(wo[k], hh[k], go);
      }
      gi = sigf(gi);
      gf = sigf(gf);
      gg = tanh_fast(gg);
      go = sigf(go);
      c = fmaf(gf, c, gi * gg);
      h = go * tanh_fast(c);

      bool act = (s < L);
      s_sum  += act ? h : 0.f;
      s_max   = act ? fmaxf(s_max, h) : s_max;
      s_last  = (s == L - 1) ? h : s_last;
    }
  }

  // stage rep = [last(16) | sum(16) | max(16)] per batch, then 48->5 linear
  __shared__ float rep[4][48];
  rep[bl][u]      = s_last;
  rep[bl][16 + u] = s_sum;
  rep[bl][32 + u] = s_max;
  __syncthreads();

  if (tid < 4 * OUTD) {
    int bo = tid / OUTD;       // local batch
    int o  = tid % OUTD;       // output idx
    float acc = b_lin[o];
    #pragma unroll
    for (int k = 0; k < 48; ++k)
      acc = fmaf(rep[bo][k], w_lin[o * 48 + k], acc);
    out[(blockIdx.x * 4 + bo) * OUTD + o] = acc;
  }
}

// ---------------- launcher ----------------
extern "C" void kernel_launch(void* const* d_in, const int* in_sizes, int n_in,
                              void* d_out, int out_size, void* d_ws, size_t ws_size,
                              hipStream_t stream)
{
  const int*   x      = (const int*)d_in[0];
  const int*   lens   = (const int*)d_in[1];
  const float* emb    = (const float*)d_in[2];
  const float* w_ih   = (const float*)d_in[3];
  const float* w_hh   = (const float*)d_in[4];
  const float* b_ih   = (const float*)d_in[5];
  const float* b_hh   = (const float*)d_in[6];
  const float* w_lin  = (const float*)d_in[7];
  const float* b_lin  = (const float*)d_in[8];
  float* out = (float*)d_out;

  float* ws     = (float*)d_ws;
  float* wt     = ws + WT_OFF;
  float* bias_t = ws + BIAS_OFF;
  float* pre    = ws + PRE_OFF;

  hipLaunchKernelGGL(k0_prep,     dim3(75),   dim3(256), 0, stream, w_ih, b_ih, b_hh, wt, bias_t);
  hipLaunchKernelGGL(k1_pregates, dim3(1024), dim3(256), 0, stream, x, emb, wt, bias_t, pre);
  hipLaunchKernelGGL(k2_lstm,     dim3(32),   dim3(64),  0, stream, lens, w_hh, w_lin, b_lin, pre, out);
}

// Round 4
// 252.473 us; speedup vs baseline: 2.4045x; 1.7566x over previous
//
#include <hip/hip_runtime.h>

// Problem constants
#define VOCAB 50000
#define EMB   300
#define HID   16
#define OUTD  5
#define BSZ   128
#define SEQ   512
#define NTOK  (BSZ*SEQ)

// ws layout (in floats):
//   [0 .. 19200)     wt     : w_ih re-transposed -> [e][u][g]  (300 x 16 x 4)
//   [19200 .. 19264) bias_t : (b_ih+b_hh) permuted [u][g]
//   [19264 .. +16M)  pre    : pre-gates [tok][u][4] (i,f,g,o per unit)
//   [.. +2048)       pad    : k2 prefetch overrun guard
#define WT_OFF   0
#define BIAS_OFF 19200
#define PRE_OFF  19264

typedef float f32x2 __attribute__((ext_vector_type(2)));

// ---------------- kernel 0: permute w_ih -> [e][u][g], fold bias ----------------
__global__ __launch_bounds__(256) void k0_prep(
    const float* __restrict__ w_ih, const float* __restrict__ b_ih,
    const float* __restrict__ b_hh, float* __restrict__ wt,
    float* __restrict__ bias_t)
{
  int i = blockIdx.x * 256 + threadIdx.x;
  if (i < 64*EMB) {
    int g = i / (16*EMB);              // gate type (i,f,g,o)
    int r = i - g * (16*EMB);
    int u = r / EMB;                   // unit
    int e = r - u * EMB;               // emb col
    wt[e * 64 + u * 4 + g] = w_ih[i];  // coalesced read
  }
  if (i < 64) {
    int u = i >> 2, g = i & 3;
    bias_t[i] = b_ih[g*16+u] + b_hh[g*16+u];
  }
}

// ---------------- kernel 1: gather + input GEMM ----------------
// 512 blocks x 256 threads. Wave q computes units [4q,4q+4) (all 4 gates).
// Each lane owns TWO tokens -> weight loads amortized 2x. The weight pointer
// goes through readfirstlane so the compiler can PROVE uniformity and
// scalarize the 1200 float4 weight loads to s_load (K$, scalar pipe) instead
// of 64-lane VMEM broadcasts through L1/TA (the round-3 bottleneck).
__global__ __launch_bounds__(256) void k1_pregates(
    const int* __restrict__ x, const float* __restrict__ emb,
    const float* __restrict__ wt, const float* __restrict__ bias_t,
    float* __restrict__ pre)
{
  const int q    = __builtin_amdgcn_readfirstlane(threadIdx.x >> 6); // uniform 0..3
  const int lane = threadIdx.x & 63;
  const int t0   = blockIdx.x * 128 + lane;   // token 0
  const int t1   = t0 + 64;                   // token 1

  const int r0 = x[t0];
  const int r1 = x[t1];
  const float4* __restrict__ e0 = (const float4*)(emb + (size_t)r0 * EMB);
  const float4* __restrict__ e1 = (const float4*)(emb + (size_t)r1 * EMB);
  const float4* __restrict__ wq = (const float4*)wt + q * 4;  // uniform base

  float4 a0[4], a1[4];
  #pragma unroll
  for (int j = 0; j < 4; ++j) { a0[j] = make_float4(0,0,0,0); a1[j] = make_float4(0,0,0,0); }

  for (int e4 = 0; e4 < EMB/4; ++e4) {   // 75 iters
    float4 v0 = e0[e4];                  // per-lane gather (16B)
    float4 v1 = e1[e4];
    #pragma unroll
    for (int ee = 0; ee < 4; ++ee) {
      const float4* wr = wq + (size_t)(e4*4 + ee) * 16;  // provably uniform
      float4 w0 = wr[0], w1 = wr[1], w2 = wr[2], w3 = wr[3];
      float s0 = (ee==0) ? v0.x : (ee==1) ? v0.y : (ee==2) ? v0.z : v0.w;
      float s1 = (ee==0) ? v1.x : (ee==1) ? v1.y : (ee==2) ? v1.z : v1.w;
      a0[0].x = fmaf(s0, w0.x, a0[0].x); a0[0].y = fmaf(s0, w0.y, a0[0].y);
      a0[0].z = fmaf(s0, w0.z, a0[0].z); a0[0].w = fmaf(s0, w0.w, a0[0].w);
      a0[1].x = fmaf(s0, w1.x, a0[1].x); a0[1].y = fmaf(s0, w1.y, a0[1].y);
      a0[1].z = fmaf(s0, w1.z, a0[1].z); a0[1].w = fmaf(s0, w1.w, a0[1].w);
      a0[2].x = fmaf(s0, w2.x, a0[2].x); a0[2].y = fmaf(s0, w2.y, a0[2].y);
      a0[2].z = fmaf(s0, w2.z, a0[2].z); a0[2].w = fmaf(s0, w2.w, a0[2].w);
      a0[3].x = fmaf(s0, w3.x, a0[3].x); a0[3].y = fmaf(s0, w3.y, a0[3].y);
      a0[3].z = fmaf(s0, w3.z, a0[3].z); a0[3].w = fmaf(s0, w3.w, a0[3].w);
      a1[0].x = fmaf(s1, w0.x, a1[0].x); a1[0].y = fmaf(s1, w0.y, a1[0].y);
      a1[0].z = fmaf(s1, w0.z, a1[0].z); a1[0].w = fmaf(s1, w0.w, a1[0].w);
      a1[1].x = fmaf(s1, w1.x, a1[1].x); a1[1].y = fmaf(s1, w1.y, a1[1].y);
      a1[1].z = fmaf(s1, w1.z, a1[1].z); a1[1].w = fmaf(s1, w1.w, a1[1].w);
      a1[2].x = fmaf(s1, w2.x, a1[2].x); a1[2].y = fmaf(s1, w2.y, a1[2].y);
      a1[2].z = fmaf(s1, w2.z, a1[2].z); a1[2].w = fmaf(s1, w2.w, a1[2].w);
      a1[3].x = fmaf(s1, w3.x, a1[3].x); a1[3].y = fmaf(s1, w3.y, a1[3].y);
      a1[3].z = fmaf(s1, w3.z, a1[3].z); a1[3].w = fmaf(s1, w3.w, a1[3].w);
    }
  }

  const float4* __restrict__ bias4 = (const float4*)bias_t;  // [16] float4
  float4* __restrict__ pre4 = (float4*)pre;
  #pragma unroll
  for (int j = 0; j < 4; ++j) {
    float4 bb = bias4[q*4 + j];
    a0[j].x += bb.x; a0[j].y += bb.y; a0[j].z += bb.z; a0[j].w += bb.w;
    a1[j].x += bb.x; a1[j].y += bb.y; a1[j].z += bb.z; a1[j].w += bb.w;
    pre4[(size_t)t0 * 16 + q*4 + j] = a0[j];
    pre4[(size_t)t1 * 16 + q*4 + j] = a1[j];
  }
}

// ---------------- kernel 2: recurrence + pooling + linear ----------------
// Fast activations: raw v_exp_f32 / v_rcp_f32 (no fp32 division sequences —
// the round-3 critical path had 5 full-precision divides per step ~250 cyc).
// Both saturate correctly: exp2->inf => rcp->0 => sig->0 / tanh->1, etc.
__device__ __forceinline__ float sig_fast(float x) {
  return __builtin_amdgcn_rcpf(1.f + __builtin_amdgcn_exp2f(-1.44269504f * x));
}
__device__ __forceinline__ float tanh_fast2(float x) {
  return fmaf(-2.f, __builtin_amdgcn_rcpf(1.f + __builtin_amdgcn_exp2f(2.88539008f * x)), 1.f);
}

// 32 blocks x 64 threads: one wave handles 4 batches x 16 units.
// h-broadcast: wave-synchronous LDS round trip (in-order DS pipe, no barrier).
// Recurrent matvec as packed f32x2 FMAs (v_pk_fma_f32) -> half the issue slots.
__global__ __launch_bounds__(64) void k2_lstm(
    const int* __restrict__ lengths,
    const float* __restrict__ w_hh,
    const float* __restrict__ w_lin,
    const float* __restrict__ b_lin,
    const float* __restrict__ pre,
    float* __restrict__ out)
{
  const int tid = threadIdx.x;
  const int u  = tid & 15;        // hidden unit
  const int bl = tid >> 4;        // local batch (0..3)
  const int b  = blockIdx.x * 4 + bl;

  // preload w_hh rows u, 16+u, 32+u, 48+u as f32x2 pairs (64 floats)
  const float4* __restrict__ wh4 = (const float4*)w_hh;
  f32x2 wi2[8], wf2[8], wg2[8], wo2[8];
  #pragma unroll
  for (int qq = 0; qq < 4; ++qq) {
    float4 t; f32x2 p;
    t = wh4[(0*HID+u)*4+qq];
    p.x=t.x; p.y=t.y; wi2[2*qq]=p;  p.x=t.z; p.y=t.w; wi2[2*qq+1]=p;
    t = wh4[(1*HID+u)*4+qq];
    p.x=t.x; p.y=t.y; wf2[2*qq]=p;  p.x=t.z; p.y=t.w; wf2[2*qq+1]=p;
    t = wh4[(2*HID+u)*4+qq];
    p.x=t.x; p.y=t.y; wg2[2*qq]=p;  p.x=t.z; p.y=t.w; wg2[2*qq+1]=p;
    t = wh4[(3*HID+u)*4+qq];
    p.x=t.x; p.y=t.y; wo2[2*qq]=p;  p.x=t.z; p.y=t.w; wo2[2*qq+1]=p;
  }

  int L = lengths[b];
  L = (L < 1) ? 1 : (L > SEQ ? SEQ : L);

  // wave-level max length (4 batches in this wave) for early exit
  int Lw = L;
  Lw = max(Lw, __shfl_xor(Lw, 16, 64));
  Lw = max(Lw, __shfl_xor(Lw, 32, 64));

  const float4* __restrict__ pp = (const float4*)pre + (size_t)b * SEQ * 16 + u;

  __shared__ float hbuf[4][16];

  float h = 0.f, c = 0.f;
  float s_sum = 0.f, s_max = -3.4e38f, s_last = 0.f;

  // software pipeline: 8-deep prefetch
  float4 buf[8];
  #pragma unroll
  for (int p = 0; p < 8; ++p) buf[p] = pp[(size_t)p * 16];

  for (int g = 0; g < SEQ/8; ++g) {
    if (g * 8 >= Lw) break;    // wave-uniform early exit
    #pragma unroll
    for (int p = 0; p < 8; ++p) {
      float4 cur = buf[p];
      buf[p] = pp[((size_t)(g+1)*8 + p) * 16];   // prefetch (pad covers overrun)
      const int s = g*8 + p;

      // wave-synchronous h broadcast: 1 ds_write + 8 ds_read_b64 (pair-aligned)
      hbuf[bl][u] = h;
      __builtin_amdgcn_wave_barrier();
      const f32x2* __restrict__ hb2 = (const f32x2*)(&hbuf[bl][0]);
      f32x2 hp[8];
      #pragma unroll
      for (int k = 0; k < 8; ++k) hp[k] = hb2[k];
      __builtin_amdgcn_wave_barrier();

      f32x2 ai, af, ag, ao;
      ai.x = cur.x; ai.y = 0.f;
      af.x = cur.y; af.y = 0.f;
      ag.x = cur.z; ag.y = 0.f;
      ao.x = cur.w; ao.y = 0.f;
      #pragma unroll
      for (int k = 0; k < 8; ++k) {
        ai = __builtin_elementwise_fma(wi2[k], hp[k], ai);
        af = __builtin_elementwise_fma(wf2[k], hp[k], af);
        ag = __builtin_elementwise_fma(wg2[k], hp[k], ag);
        ao = __builtin_elementwise_fma(wo2[k], hp[k], ao);
      }
      float gi = ai.x + ai.y;
      float gf = af.x + af.y;
      float gg = ag.x + ag.y;
      float go = ao.x + ao.y;

      gi = sig_fast(gi);
      gf = sig_fast(gf);
      gg = tanh_fast2(gg);
      go = sig_fast(go);
      c = fmaf(gf, c, gi * gg);
      h = go * tanh_fast2(c);

      bool act = (s < L);
      s_sum  += act ? h : 0.f;
      s_max   = act ? fmaxf(s_max, h) : s_max;
      s_last  = (s == L - 1) ? h : s_last;
    }
  }

  // stage rep = [last(16) | sum(16) | max(16)] per batch, then 48->5 linear
  __shared__ float rep[4][48];
  rep[bl][u]      = s_last;
  rep[bl][16 + u] = s_sum;
  rep[bl][32 + u] = s_max;
  __syncthreads();

  if (tid < 4 * OUTD) {
    int bo = tid / OUTD;       // local batch
    int o  = tid % OUTD;       // output idx
    float acc = b_lin[o];
    #pragma unroll
    for (int k = 0; k < 48; ++k)
      acc = fmaf(rep[bo][k], w_lin[o * 48 + k], acc);
    out[(blockIdx.x * 4 + bo) * OUTD + o] = acc;
  }
}

// ---------------- launcher ----------------
extern "C" void kernel_launch(void* const* d_in, const int* in_sizes, int n_in,
                              void* d_out, int out_size, void* d_ws, size_t ws_size,
                              hipStream_t stream)
{
  const int*   x      = (const int*)d_in[0];
  const int*   lens   = (const int*)d_in[1];
  const float* emb    = (const float*)d_in[2];
  const float* w_ih   = (const float*)d_in[3];
  const float* w_hh   = (const float*)d_in[4];
  const float* b_ih   = (const float*)d_in[5];
  const float* b_hh   = (const float*)d_in[6];
  const float* w_lin  = (const float*)d_in[7];
  const float* b_lin  = (const float*)d_in[8];
  float* out = (float*)d_out;

  float* ws     = (float*)d_ws;
  float* wt     = ws + WT_OFF;
  float* bias_t = ws + BIAS_OFF;
  float* pre    = ws + PRE_OFF;

  hipLaunchKernelGGL(k0_prep,     dim3(75),  dim3(256), 0, stream, w_ih, b_ih, b_hh, wt, bias_t);
  hipLaunchKernelGGL(k1_pregates, dim3(512), dim3(256), 0, stream, x, emb, wt, bias_t, pre);
  hipLaunchKernelGGL(k2_lstm,     dim3(32),  dim3(64),  0, stream, lens, w_hh, w_lin, b_lin, pre, out);
}